// Round 1
// baseline (8257.729 us; speedup 1.0000x reference)
//
#include <hip/hip_runtime.h>
#include <cstdint>

typedef unsigned short u16;
typedef unsigned int   u32;
using short8 = __attribute__((ext_vector_type(8))) short;
using f32x4  = __attribute__((ext_vector_type(4))) float;

#define S_   2048
#define D_   1024
#define NTOK 4096   /* B*S */

__device__ __forceinline__ u16 f2bf(float f){
  u32 u = __float_as_uint(f);
  u32 r = u + 0x7fffu + ((u >> 16) & 1u);   // RNE
  return (u16)(r >> 16);
}
__device__ __forceinline__ float bf2f(u16 h){
  return __uint_as_float(((u32)h) << 16);
}
__device__ __forceinline__ void gld16(const void* g, void* l){
  __builtin_amdgcn_global_load_lds((__attribute__((address_space(1))) void*)(void*)g,
                                   (__attribute__((address_space(3))) void*)l, 16, 0, 0);
}

// ---------------------------------------------------------------------------
// Generic bf16 MFMA GEMM: C[M,N] = A(bf16,row-major)[M,K] * B[K,N]
//   BTRANS=0 (NN): B is [K][ldb] (f32 or bf16 per F_BF16B), reg-staged with
//                  on-the-fly f32->bf16 convert + transpose into padded LDS.
//   BTRANS=1 (NT): B arg is Bt row-major [N][ldb] bf16 (k contiguous),
//                  staged via global_load_lds like A.  (used for Q·K^T)
// 128x128 tile, BK=32, 256 thr = 4 waves (2x2 of 64x64), 16x16x32 bf16 MFMA.
// ---------------------------------------------------------------------------
enum { F_OUTBF16=1, F_BIAS=2, F_RELU=4, F_RESID=8, F_GATEACC=16, F_BF16B=32, F_BTRANS=64 };

template<int FLAGS>
__global__ void __launch_bounds__(256, 2)
gemm_k(const u16* __restrict__ A, int lda, long sAz,
       const void* __restrict__ B, int ldb, long sBz,
       void* __restrict__ out, int ldo, long sOz,
       const float* __restrict__ bias,
       const float* __restrict__ resid,
       const float* __restrict__ gate,
       int K, int ncols)
{
  constexpr int BM = 128, BN = 128, BK = 32;
  constexpr int BKP = (FLAGS & F_BTRANS) ? 32 : 40;   // pad NN B-LDS rows (bank conflicts)
  const int tid = threadIdx.x;
  const int w = tid >> 6, l = tid & 63;
  const int wr = w >> 1, wc = w & 1;
  const int tn = blockIdx.x, tm = blockIdx.y, z = blockIdx.z;
  const int ncol0 = tn * BN;

  const u16*   Ab  = A + (long)z*sAz + (long)tm*BM*lda;
  const float* Bf  = (const float*)B + (long)z*sBz;
  const u16*   Bh  = (const u16*)B + (long)z*sBz;
  const u16*   Btb = Bh + (long)ncol0*ldb;            // NT tile base

  __shared__ __align__(16) u16 As[2][BM*BK];
  __shared__ __align__(16) u16 Bs[2][BN*BKP];

  f32x4 zero = {0.f,0.f,0.f,0.f};
  f32x4 acc[4][4];
  #pragma unroll
  for (int i=0;i<4;i++)
    #pragma unroll
    for (int j=0;j<4;j++) acc[i][j] = zero;

  const int NK = K >> 5;
  const int bn_local = tid & 127;
  const int rbase = (tid >> 7) * 16;
  const int gcol = ncol0 + bn_local;
  const bool bok = gcol < ncols;
  u16 hv[16];

  auto stageA = [&](int buf, int kt){
    const int k0 = kt*BK;
    #pragma unroll
    for (int i=0;i<2;i++){
      const int c = i*256 + w*64 + l;
      const int row = c >> 2, seg = c & 3;
      gld16(Ab + (long)row*lda + k0 + seg*8, &As[buf][(i*256 + w*64)*8]);
    }
  };
  auto stageBt = [&](int buf, int kt){
    const int k0 = kt*BK;
    #pragma unroll
    for (int i=0;i<2;i++){
      const int c = i*256 + w*64 + l;
      const int row = c >> 2, seg = c & 3;
      gld16(Btb + (long)row*ldb + k0 + seg*8, &Bs[buf][(i*256 + w*64)*8]);
    }
  };
  auto loadB = [&](int kt){
    const int k0 = kt*BK;
    #pragma unroll
    for (int i=0;i<16;i++){
      const long r = (long)(k0 + rbase + i);
      if constexpr (FLAGS & F_BF16B) hv[i] = bok ? Bh[r*ldb + gcol] : (u16)0;
      else                           hv[i] = bok ? f2bf(Bf[r*ldb + gcol]) : (u16)0;
    }
  };
  auto writeB = [&](int buf){
    u32 p[8];
    #pragma unroll
    for (int i=0;i<8;i++) p[i] = (u32)hv[2*i] | ((u32)hv[2*i+1] << 16);
    u16* dst = &Bs[buf][bn_local*BKP + rbase];
    uint4 q0; q0.x=p[0]; q0.y=p[1]; q0.z=p[2]; q0.w=p[3];
    uint4 q1; q1.x=p[4]; q1.y=p[5]; q1.z=p[6]; q1.w=p[7];
    *(uint4*)(dst)     = q0;
    *(uint4*)(dst + 8) = q1;
  };

  // prologue: stage k-step 0 into buf 0
  if constexpr (FLAGS & F_BTRANS) stageBt(0,0); else loadB(0);
  stageA(0,0);
  if constexpr (!(FLAGS & F_BTRANS)) writeB(0);
  __syncthreads();

  for (int kt=0; kt<NK; ++kt){
    const int cur = kt & 1, nxt = cur ^ 1;
    const bool more = (kt+1) < NK;
    if (more){
      stageA(nxt, kt+1);
      if constexpr (FLAGS & F_BTRANS) stageBt(nxt, kt+1);
      else loadB(kt+1);
    }
    short8 a[4], b[4];
    #pragma unroll
    for (int m=0;m<4;m++){
      const int arow = wr*64 + m*16 + (l & 15);
      a[m] = *(const short8*)&As[cur][arow*BK + (l>>4)*8];
    }
    #pragma unroll
    for (int n=0;n<4;n++){
      const int brow = wc*64 + n*16 + (l & 15);
      b[n] = *(const short8*)&Bs[cur][brow*BKP + (l>>4)*8];
    }
    #pragma unroll
    for (int m=0;m<4;m++)
      #pragma unroll
      for (int n=0;n<4;n++)
        acc[m][n] = __builtin_amdgcn_mfma_f32_16x16x32_bf16(a[m], b[n], acc[m][n], 0, 0, 0);
    if (more){ if constexpr (!(FLAGS & F_BTRANS)) writeB(nxt); }
    __syncthreads();
  }

  // epilogue  (C/D layout: col = lane&15, row = (lane>>4)*4 + reg  [m89])
  float* outf = (float*)out + (long)z*sOz;
  u16*   outh = (u16*)out + (long)z*sOz;
  const long row0 = (long)tm*BM + wr*64;
  #pragma unroll
  for (int m=0;m<4;m++){
    #pragma unroll
    for (int n=0;n<4;n++){
      const int col = ncol0 + wc*64 + n*16 + (l & 15);
      if (col < ncols){
        #pragma unroll
        for (int r=0;r<4;r++){
          const long row = row0 + m*16 + ((l>>4)*4) + r;
          float v = acc[m][n][r];
          if constexpr (FLAGS & F_BIAS) v += bias[col];
          if constexpr (FLAGS & F_RELU) v = fmaxf(v, 0.f);
          const long off = row*(long)ldo + col;
          if constexpr (FLAGS & F_GATEACC){
            const float g = gate ? gate[row*8] : 1.0f;
            outf[off] += g * v;
          } else if constexpr (FLAGS & F_RESID){
            outf[off] = resid[off] + v;
          } else if constexpr (FLAGS & F_OUTBF16){
            outh[off] = f2bf(v);
          } else {
            outf[off] = v;
          }
        }
      }
    }
  }
}

// ---------------------------------------------------------------------------
template<bool WF32>
__global__ void rmsnorm_k(const float* __restrict__ x, const float* __restrict__ w,
                          u16* __restrict__ ob, float* __restrict__ of)
{
  const int row = blockIdx.x, t = threadIdx.x;
  const float4 v = ((const float4*)(x + (long)row*D_))[t];
  float ss = v.x*v.x + v.y*v.y + v.z*v.z + v.w*v.w;
  #pragma unroll
  for (int o=32;o>0;o>>=1) ss += __shfl_down(ss, o);
  __shared__ float red[4];
  if ((t&63)==0) red[t>>6] = ss;
  __syncthreads();
  const float scale = rsqrtf((red[0]+red[1]+red[2]+red[3])*(1.0f/D_) + 1e-6f);
  const float4 wv = ((const float4*)w)[t];
  const float o0=v.x*scale*wv.x, o1=v.y*scale*wv.y, o2=v.z*scale*wv.z, o3=v.w*scale*wv.w;
  const long base = (long)row*D_ + t*4;
  uint2 p; p.x = (u32)f2bf(o0) | ((u32)f2bf(o1)<<16);
  p.y = (u32)f2bf(o2) | ((u32)f2bf(o3)<<16);
  *(uint2*)&ob[base] = p;
  if constexpr (WF32) *(float4*)&of[base] = make_float4(o0,o1,o2,o3);
}

// qf = [q | rope(qr)], kf = [k | rope(kr)]  per (token, head, pair j)
__global__ void rope_concat_k(const u16* __restrict__ qt, const u16* __restrict__ qrt,
                              const u16* __restrict__ kt, const u16* __restrict__ krt,
                              const float* __restrict__ fc, const float* __restrict__ fs,
                              u16* __restrict__ qf, u16* __restrict__ kf)
{
  const int idx = blockIdx.x*256 + threadIdx.x;   // NTOK*16*32 threads
  const int j = idx & 31, h = (idx>>5) & 15, bs = idx >> 9;
  if (bs >= NTOK) return;
  const int s = bs & (S_-1);
  const float c = fc[s*32+j], sn = fs[s*32+j];
  const long ib = (long)bs*1024 + h*64 + 2*j;
  const long ob = (long)bs*2048 + h*128 + 2*j;
  qf[ob]   = qt[ib];  qf[ob+1] = qt[ib+1];
  kf[ob]   = kt[ib];  kf[ob+1] = kt[ib+1];
  float x0 = bf2f(qrt[ib]), x1 = bf2f(qrt[ib+1]);
  qf[ob+64] = f2bf(x0*c - x1*sn);
  qf[ob+65] = f2bf(x0*sn + x1*c);
  x0 = bf2f(krt[ib]); x1 = bf2f(krt[ib+1]);
  kf[ob+64] = f2bf(x0*c - x1*sn);
  kf[ob+65] = f2bf(x0*sn + x1*c);
}

// row softmax of scores/8, in place (bf16), row length 2048
__global__ void softmax_k(u16* __restrict__ sc)
{
  const long row = blockIdx.x;
  const int t = threadIdx.x;
  u16* p = sc + row*2048;
  const uint4 raw = ((const uint4*)p)[t];
  float v[8];
  v[0]=bf2f((u16)(raw.x&0xffffu)); v[1]=bf2f((u16)(raw.x>>16));
  v[2]=bf2f((u16)(raw.y&0xffffu)); v[3]=bf2f((u16)(raw.y>>16));
  v[4]=bf2f((u16)(raw.z&0xffffu)); v[5]=bf2f((u16)(raw.z>>16));
  v[6]=bf2f((u16)(raw.w&0xffffu)); v[7]=bf2f((u16)(raw.w>>16));
  float m = v[0];
  #pragma unroll
  for (int i=1;i<8;i++) m = fmaxf(m, v[i]);
  #pragma unroll
  for (int o=32;o>0;o>>=1) m = fmaxf(m, __shfl_down(m, o));
  __shared__ float redm[4], reds[4];
  if ((t&63)==0) redm[t>>6]=m;
  __syncthreads();
  m = fmaxf(fmaxf(redm[0],redm[1]), fmaxf(redm[2],redm[3]));
  float sum = 0.f;
  #pragma unroll
  for (int i=0;i<8;i++){ v[i] = expf((v[i]-m)*0.125f); sum += v[i]; }
  #pragma unroll
  for (int o=32;o>0;o>>=1) sum += __shfl_down(sum, o);
  if ((t&63)==0) reds[t>>6]=sum;
  __syncthreads();
  const float inv = 1.f/(reds[0]+reds[1]+reds[2]+reds[3]);
  uint4 o4;
  o4.x = (u32)f2bf(v[0]*inv) | ((u32)f2bf(v[1]*inv)<<16);
  o4.y = (u32)f2bf(v[2]*inv) | ((u32)f2bf(v[3]*inv)<<16);
  o4.z = (u32)f2bf(v[4]*inv) | ((u32)f2bf(v[5]*inv)<<16);
  o4.w = (u32)f2bf(v[6]*inv) | ((u32)f2bf(v[7]*inv)<<16);
  ((uint4*)p)[t] = o4;
}

// noisy top-2 router -> dense gate[NTOK][8] (2 nonzero)
__global__ void router_k(const float* __restrict__ h2, const float* __restrict__ wr,
                         const float* __restrict__ br, const float* __restrict__ wn,
                         const float* __restrict__ bn, const float* __restrict__ noise,
                         float* __restrict__ gate)
{
  const int tok = blockIdx.x, t = threadIdx.x;
  const float4 xv = ((const float4*)(h2 + (long)tok*D_))[t];
  const float xs[4] = {xv.x, xv.y, xv.z, xv.w};
  float ar[8], an[8];
  #pragma unroll
  for (int e=0;e<8;e++){ ar[e]=0.f; an[e]=0.f; }
  #pragma unroll
  for (int i=0;i<4;i++){
    const int d = t*4+i;
    const float* wrr = wr + d*8;
    const float* wnr = wn + d*8;
    #pragma unroll
    for (int e=0;e<8;e++){ ar[e] += xs[i]*wrr[e]; an[e] += xs[i]*wnr[e]; }
  }
  #pragma unroll
  for (int e=0;e<8;e++){
    #pragma unroll
    for (int o=32;o>0;o>>=1){ ar[e] += __shfl_down(ar[e], o); an[e] += __shfl_down(an[e], o); }
  }
  __shared__ float rr[4][8], rn[4][8];
  if ((t&63)==0){
    const int w4 = t>>6;
    #pragma unroll
    for (int e=0;e<8;e++){ rr[w4][e]=ar[e]; rn[w4][e]=an[e]; }
  }
  __syncthreads();
  if (t==0){
    float nz[8];
    #pragma unroll
    for (int e=0;e<8;e++){
      const float r  = rr[0][e]+rr[1][e]+rr[2][e]+rr[3][e] + br[e];
      const float ns = rn[0][e]+rn[1][e]+rn[2][e]+rn[3][e] + bn[e];
      const float sp = (ns > 20.f) ? ns : log1pf(expf(ns));
      nz[e] = r + noise[(long)tok*8+e]*sp;
    }
    int i0 = 0;
    #pragma unroll
    for (int e=1;e<8;e++) if (nz[e] > nz[i0]) i0 = e;
    int i1 = 0; float best = -3.0e38f;
    #pragma unroll
    for (int e=0;e<8;e++) if (e != i0 && nz[e] > best){ best = nz[e]; i1 = e; }
    const float e1  = expf(nz[i1]-nz[i0]);
    const float inv = 1.f/(1.f+e1);
    float go[8];
    #pragma unroll
    for (int e=0;e<8;e++) go[e]=0.f;
    go[i0] = inv; go[i1] = e1*inv;
    #pragma unroll
    for (int e=0;e<8;e++) gate[(long)tok*8+e] = go[e];
  }
}

__global__ void combine_k(const float* __restrict__ a, const float* __restrict__ b,
                          const float* __restrict__ c, float* __restrict__ o, long n4)
{
  long i = (long)blockIdx.x*blockDim.x + threadIdx.x;
  const long stride = (long)gridDim.x*blockDim.x;
  for (; i<n4; i+=stride){
    const float4 va = ((const float4*)a)[i];
    const float4 vb = ((const float4*)b)[i];
    const float4 vc = ((const float4*)c)[i];
    ((float4*)o)[i] = make_float4(va.x+vb.x+vc.x, va.y+vb.y+vc.y,
                                  va.z+vb.z+vc.z, va.w+vb.w+vc.w);
  }
}

// ---------------------------------------------------------------------------
extern "C" void kernel_launch(void* const* d_in, const int* in_sizes, int n_in,
                              void* d_out, int out_size, void* d_ws, size_t ws_size,
                              hipStream_t stream)
{
  const float* x      = (const float*)d_in[0];
  const float* fcos   = (const float*)d_in[1];
  const float* fsin   = (const float*)d_in[2];
  const float* rnoise = (const float*)d_in[3];
  const float* rms1w  = (const float*)d_in[4];
  const float* rms2w  = (const float*)d_in[5];
  const float* w_lq   = (const float*)d_in[6];
  const float* w_lkv  = (const float*)d_in[7];
  const float* w_q    = (const float*)d_in[8];
  const float* w_k    = (const float*)d_in[9];
  const float* w_v    = (const float*)d_in[10];
  const float* w_qr   = (const float*)d_in[11];
  const float* b_qr   = (const float*)d_in[12];
  const float* w_kr   = (const float*)d_in[13];
  const float* b_kr   = (const float*)d_in[14];
  const float* w_o    = (const float*)d_in[15];
  const float* b_o    = (const float*)d_in[16];
  const float* w_route= (const float*)d_in[17];
  const float* b_route= (const float*)d_in[18];
  const float* w_noise= (const float*)d_in[19];
  const float* b_noise= (const float*)d_in[20];
  const float* rW1    = (const float*)d_in[21];
  const float* rb1    = (const float*)d_in[22];
  const float* rW2    = (const float*)d_in[23];
  const float* rb2    = (const float*)d_in[24];
  const float* sW1    = (const float*)d_in[25];
  const float* sb1    = (const float*)d_in[26];
  const float* sW2    = (const float*)d_in[27];
  const float* sb2    = (const float*)d_in[28];

  if (ws_size < 195166208ULL) return;  // clean fail if scratch too small

  char* ws = (char*)d_ws;
  u16*   h_bf    = (u16*)(ws + 0);          // 4096x1024 bf16
  u16*   cq_bf   = (u16*)(ws + 8388608);    // 4096x768
  u16*   ckv_bf  = (u16*)(ws + 14680064);   // 4096x512
  u16*   v_bf    = (u16*)(ws + 18874368);   // 4096x1024
  u16*   qf      = (u16*)(ws + 27262976);   // 4096x2048
  u16*   kf      = (u16*)(ws + 44040192);   // 4096x2048
  u16*   attn_bf = (u16*)(ws + 60817408);   // 4096x1024
  float* x1      = (float*)(ws + 69206016); // 4096x1024 f32
  float* h2f     = (float*)(ws + 85983232); // 4096x1024 f32
  u16*   h2_bf   = (u16*)(ws + 102760448);  // 4096x1024
  float* gate    = (float*)(ws + 111149056);// 4096x8 f32
  float* facc    = (float*)(ws + 111280128);// 4096x1024 f32
  char*  tmpz    = ws + 128057344;          // 67 MB aliased zone
  u16*   q_tmp   = (u16*)(tmpz);
  u16*   qr_tmp  = (u16*)(tmpz + 8388608);
  u16*   k_tmp   = (u16*)(tmpz + 16777216);
  u16*   kr_tmp  = (u16*)(tmpz + 25165824);
  u16*   scores  = (u16*)(tmpz);            // reused after rope
  u16*   inter   = (u16*)(tmpz);            // reused after attention

  const dim3 blk(256,1,1);

  // h = rmsnorm(x) -> bf16
  rmsnorm_k<false><<<NTOK, blk, 0, stream>>>(x, rms1w, h_bf, nullptr);

  // latent projections
  gemm_k<F_OUTBF16><<<dim3(6,32,1), blk, 0, stream>>>(h_bf,1024,0, w_lq,768,0, cq_bf,768,0, nullptr,nullptr,nullptr, 1024, 768);
  gemm_k<F_OUTBF16><<<dim3(4,32,1), blk, 0, stream>>>(h_bf,1024,0, w_lkv,512,0, ckv_bf,512,0, nullptr,nullptr,nullptr, 1024, 512);

  // q/qr/k/kr/v
  gemm_k<F_OUTBF16><<<dim3(8,32,1), blk, 0, stream>>>(cq_bf,768,0, w_q,1024,0, q_tmp,1024,0, nullptr,nullptr,nullptr, 768, 1024);
  gemm_k<F_OUTBF16|F_BIAS><<<dim3(8,32,1), blk, 0, stream>>>(cq_bf,768,0, w_qr,1024,0, qr_tmp,1024,0, b_qr,nullptr,nullptr, 768, 1024);
  gemm_k<F_OUTBF16><<<dim3(8,32,1), blk, 0, stream>>>(ckv_bf,512,0, w_k,1024,0, k_tmp,1024,0, nullptr,nullptr,nullptr, 512, 1024);
  gemm_k<F_OUTBF16|F_BIAS><<<dim3(8,32,1), blk, 0, stream>>>(h_bf,1024,0, w_kr,1024,0, kr_tmp,1024,0, b_kr,nullptr,nullptr, 1024, 1024);
  gemm_k<F_OUTBF16><<<dim3(8,32,1), blk, 0, stream>>>(ckv_bf,512,0, w_v,1024,0, v_bf,1024,0, nullptr,nullptr,nullptr, 512, 1024);

  rope_concat_k<<<8192, blk, 0, stream>>>(q_tmp, qr_tmp, k_tmp, kr_tmp, fcos, fsin, qf, kf);

  // attention, 4 chunks of 8 (b,h) slabs (scores chunk = 67MB, L3-resident)
  for (int c=0;c<4;c++){
    const int b = c >> 1, h0 = (c & 1) * 8;
    const u16* qfs = qf + (long)b*4194304 + h0*128;
    const u16* kfs = kf + (long)b*4194304 + h0*128;
    gemm_k<F_OUTBF16|F_BTRANS><<<dim3(16,16,8), blk, 0, stream>>>(
        qfs,2048,128, kfs,2048,128, scores,2048,4194304L,
        nullptr,nullptr,nullptr, 128, 2048);
    softmax_k<<<16384, blk, 0, stream>>>(scores);
    const u16* vs = v_bf + (long)b*2097152 + h0*64;
    u16* ao = attn_bf + (long)b*2097152 + h0*64;
    gemm_k<F_OUTBF16|F_BF16B><<<dim3(1,16,8), blk, 0, stream>>>(
        scores,2048,4194304L, vs,1024,64, ao,1024,64,
        nullptr,nullptr,nullptr, 2048, 64);
  }

  // x1 = x + attn@w_o + b_o ; h2 = rmsnorm(x1)
  gemm_k<F_BIAS|F_RESID><<<dim3(8,32,1), blk, 0, stream>>>(attn_bf,1024,0, w_o,1024,0, x1,1024,0, b_o, x, nullptr, 1024, 1024);
  rmsnorm_k<true><<<NTOK, blk, 0, stream>>>(x1, rms2w, h2_bf, h2f);

  // router + gates
  router_k<<<NTOK, blk, 0, stream>>>(h2f, w_route, b_route, w_noise, b_noise, rnoise, gate);
  hipMemsetAsync(facc, 0, 16777216, stream);

  // routed experts (dense, gate-weighted accumulate)
  for (int e=0;e<8;e++){
    gemm_k<F_OUTBF16|F_BIAS|F_RELU><<<dim3(32,32,1), blk, 0, stream>>>(
        h2_bf,1024,0, rW1 + (long)e*4194304, 4096,0, inter,4096,0,
        rb1 + e*4096, nullptr, nullptr, 1024, 4096);
    gemm_k<F_BIAS|F_GATEACC><<<dim3(8,32,1), blk, 0, stream>>>(
        inter,4096,0, rW2 + (long)e*4194304, 1024,0, facc,1024,0,
        rb2 + e*1024, nullptr, gate + e, 4096, 1024);
  }
  // shared experts (gate = 1)
  for (int j=0;j<2;j++){
    gemm_k<F_OUTBF16|F_BIAS|F_RELU><<<dim3(32,32,1), blk, 0, stream>>>(
        h2_bf,1024,0, sW1 + (long)j*4194304, 4096,0, inter,4096,0,
        sb1 + j*4096, nullptr, nullptr, 1024, 4096);
    gemm_k<F_BIAS|F_GATEACC><<<dim3(8,32,1), blk, 0, stream>>>(
        inter,4096,0, sW2 + (long)j*4194304, 1024,0, facc,1024,0,
        sb2 + j*1024, nullptr, nullptr, 4096, 1024);
  }

  // out = x1 + h2 + f
  combine_k<<<2048, blk, 0, stream>>>(x1, h2f, facc, (float*)d_out, 1048576L);
}

// Round 2
// 2146.694 us; speedup vs baseline: 3.8467x; 3.8467x over previous
//
#include <hip/hip_runtime.h>
#include <cstdint>

typedef unsigned short u16;
typedef unsigned int   u32;
using short8 = __attribute__((ext_vector_type(8))) short;
using f32x4  = __attribute__((ext_vector_type(4))) float;

#define S_   2048
#define D_   1024
#define NTOK 4096   /* B*S */

__device__ __forceinline__ u16 f2bf(float f){
  u32 u = __float_as_uint(f);
  u32 r = u + 0x7fffu + ((u >> 16) & 1u);   // RNE
  return (u16)(r >> 16);
}
__device__ __forceinline__ float bf2f(u16 h){
  return __uint_as_float(((u32)h) << 16);
}
__device__ __forceinline__ void gld16(const void* g, void* l){
  __builtin_amdgcn_global_load_lds((__attribute__((address_space(1))) void*)(void*)g,
                                   (__attribute__((address_space(3))) void*)l, 16, 0, 0);
}

// ---------------------------------------------------------------------------
// bf16 MFMA GEMM, NT only: C[M,N] = A[M,K] (row-major bf16, ld=lda) *
//                                   Bt[N,K] (row-major bf16, ld=ldb)^T
// 128x128 tile, BK=32, 256 thr = 4 waves (2x2 of 64x64), 16x16x32 bf16 MFMA.
// Both operands staged via global_load_lds (16B), double-buffered LDS.
// F_SPLITK: z indexes a K-half; A cols += z*sAz, Bt k-off += z*sBz,
//           GATEACC output goes to out (z=0) / out2 (z=1); bias only on z=0.
// ---------------------------------------------------------------------------
enum { F_OUTBF16=1, F_BIAS=2, F_RELU=4, F_RESID=8, F_GATEACC=16, F_SPLITK=32 };

template<int FLAGS>
__global__ void __launch_bounds__(256, 4)
gemm_k(const u16* __restrict__ A, int lda, long sAz,
       const u16* __restrict__ Bt, int ldb, long sBz,
       void* __restrict__ out, int ldo, long sOz,
       const float* __restrict__ bias,
       const float* __restrict__ resid,
       const float* __restrict__ gate,
       float* __restrict__ out2,
       int K, int ncols)
{
  constexpr int BM = 128, BN = 128, BK = 32;
  const int tid = threadIdx.x;
  const int w = tid >> 6, l = tid & 63;
  const int wr = w >> 1, wc = w & 1;
  const int tn = blockIdx.x, tm = blockIdx.y, z = blockIdx.z;
  const int ncol0 = tn * BN;

  const u16* Ab  = A  + (long)z*sAz + (long)tm*BM*lda;
  const u16* Btb = Bt + (long)z*sBz + (long)ncol0*ldb;

  __shared__ __align__(16) u16 As[2][BM*BK];
  __shared__ __align__(16) u16 Bs[2][BN*BK];

  f32x4 zero = {0.f,0.f,0.f,0.f};
  f32x4 acc[4][4];
  #pragma unroll
  for (int i=0;i<4;i++)
    #pragma unroll
    for (int j=0;j<4;j++) acc[i][j] = zero;

  const int NK = K >> 5;

  auto stage = [&](int buf, int kt){
    const int k0 = kt*BK;
    #pragma unroll
    for (int i=0;i<2;i++){
      const int c = i*256 + tid;
      const int row = c >> 2, seg = c & 3;
      gld16(Ab  + (long)row*lda + k0 + seg*8, &As[buf][(i*256 + w*64)*8]);
      gld16(Btb + (long)row*ldb + k0 + seg*8, &Bs[buf][(i*256 + w*64)*8]);
    }
  };

  stage(0,0);
  __syncthreads();

  for (int kt=0; kt<NK; ++kt){
    const int cur = kt & 1, nxt = cur ^ 1;
    if (kt+1 < NK) stage(nxt, kt+1);
    short8 a[4], b[4];
    #pragma unroll
    for (int m=0;m<4;m++){
      const int arow = wr*64 + m*16 + (l & 15);
      a[m] = *(const short8*)&As[cur][arow*BK + (l>>4)*8];
    }
    #pragma unroll
    for (int n=0;n<4;n++){
      const int brow = wc*64 + n*16 + (l & 15);
      b[n] = *(const short8*)&Bs[cur][brow*BK + (l>>4)*8];
    }
    #pragma unroll
    for (int m=0;m<4;m++)
      #pragma unroll
      for (int n=0;n<4;n++)
        acc[m][n] = __builtin_amdgcn_mfma_f32_16x16x32_bf16(a[m], b[n], acc[m][n], 0, 0, 0);
    __syncthreads();
  }

  // epilogue  (C/D layout: col = lane&15, row = (lane>>4)*4 + reg  [m89])
  float* outf = (float*)out + (long)z*sOz;
  u16*   outh = (u16*)out + (long)z*sOz;
  const long row0 = (long)tm*BM + wr*64;
  #pragma unroll
  for (int m=0;m<4;m++){
    #pragma unroll
    for (int n=0;n<4;n++){
      const int col = ncol0 + wc*64 + n*16 + (l & 15);
      if (col < ncols){
        #pragma unroll
        for (int r=0;r<4;r++){
          const long row = row0 + m*16 + ((l>>4)*4) + r;
          float v = acc[m][n][r];
          if constexpr (FLAGS & F_BIAS){
            if (!(FLAGS & F_SPLITK) || z == 0) v += bias[col];
          }
          if constexpr (FLAGS & F_RELU) v = fmaxf(v, 0.f);
          const long off = row*(long)ldo + col;
          if constexpr (FLAGS & F_GATEACC){
            const float g = gate ? gate[row*8] : 1.0f;
            float* dst = ((FLAGS & F_SPLITK) && z) ? out2 : outf;
            dst[off] += g * v;
          } else if constexpr (FLAGS & F_RESID){
            outf[off] = resid[off] + v;
          } else if constexpr (FLAGS & F_OUTBF16){
            outh[off] = f2bf(v);
          } else {
            outf[off] = v;
          }
        }
      }
    }
  }
}

// ---------------------------------------------------------------------------
// transpose f32 [K][N] (ld=N) -> bf16 [N][K] (ld=K).  dims multiples of 32.
__global__ void tpose_k(const float* __restrict__ src, u16* __restrict__ dst,
                        int K, int N)
{
  __shared__ u16 tile[32][36];
  const int t = threadIdx.x;
  const int n0 = blockIdx.x*32, k0 = blockIdx.y*32;
  const int lr = t >> 3, lc = (t & 7) * 4;
  const float4 v = *(const float4*)&src[(long)(k0+lr)*N + n0 + lc];
  ushort4 tv; tv.x=f2bf(v.x); tv.y=f2bf(v.y); tv.z=f2bf(v.z); tv.w=f2bf(v.w);
  *(ushort4*)&tile[lr][lc] = tv;
  __syncthreads();
  ushort4 o;
  o.x = tile[lc+0][lr]; o.y = tile[lc+1][lr];
  o.z = tile[lc+2][lr]; o.w = tile[lc+3][lr];
  *(ushort4*)&dst[(long)(n0+lr)*K + k0 + lc] = o;
}

// v_bf [b][s][h*64+d] -> vt [(b*16+h)][d][s]   (bf16 -> bf16 transpose)
__global__ void vt_k(const u16* __restrict__ src, u16* __restrict__ dst)
{
  __shared__ u16 tile[32][36];
  const int t = threadIdx.x;
  const int z = blockIdx.z;            // b*16+h
  const int b = z >> 4, h = z & 15;
  const int s0 = blockIdx.x*32, d0 = blockIdx.y*32;
  const int lr = t >> 3, lc = (t & 7) * 4;
  ushort4 v = *(const ushort4*)&src[(long)(b*2048 + s0+lr)*1024 + h*64 + d0 + lc];
  *(ushort4*)&tile[lr][lc] = v;
  __syncthreads();
  ushort4 o;
  o.x = tile[lc+0][lr]; o.y = tile[lc+1][lr];
  o.z = tile[lc+2][lr]; o.w = tile[lc+3][lr];
  *(ushort4*)&dst[(long)z*131072 + (long)(d0+lr)*2048 + s0 + lc] = o;
}

// ---------------------------------------------------------------------------
template<bool WF32>
__global__ void rmsnorm_k(const float* __restrict__ x, const float* __restrict__ w,
                          u16* __restrict__ ob, float* __restrict__ of)
{
  const int row = blockIdx.x, t = threadIdx.x;
  const float4 v = ((const float4*)(x + (long)row*D_))[t];
  float ss = v.x*v.x + v.y*v.y + v.z*v.z + v.w*v.w;
  #pragma unroll
  for (int o=32;o>0;o>>=1) ss += __shfl_down(ss, o);
  __shared__ float red[4];
  if ((t&63)==0) red[t>>6] = ss;
  __syncthreads();
  const float scale = rsqrtf((red[0]+red[1]+red[2]+red[3])*(1.0f/D_) + 1e-6f);
  const float4 wv = ((const float4*)w)[t];
  const float o0=v.x*scale*wv.x, o1=v.y*scale*wv.y, o2=v.z*scale*wv.z, o3=v.w*scale*wv.w;
  const long base = (long)row*D_ + t*4;
  uint2 p; p.x = (u32)f2bf(o0) | ((u32)f2bf(o1)<<16);
  p.y = (u32)f2bf(o2) | ((u32)f2bf(o3)<<16);
  *(uint2*)&ob[base] = p;
  if constexpr (WF32) *(float4*)&of[base] = make_float4(o0,o1,o2,o3);
}

// qf = [q | rope(qr)], kf = [k | rope(kr)]
__global__ void rope_concat_k(const u16* __restrict__ qt, const u16* __restrict__ qrt,
                              const u16* __restrict__ kt, const u16* __restrict__ krt,
                              const float* __restrict__ fc, const float* __restrict__ fs,
                              u16* __restrict__ qf, u16* __restrict__ kf)
{
  const int idx = blockIdx.x*256 + threadIdx.x;   // NTOK*16*32 threads
  const int j = idx & 31, h = (idx>>5) & 15, bs = idx >> 9;
  if (bs >= NTOK) return;
  const int s = bs & (S_-1);
  const float c = fc[s*32+j], sn = fs[s*32+j];
  const long ib = (long)bs*1024 + h*64 + 2*j;
  const long ob = (long)bs*2048 + h*128 + 2*j;
  *(u32*)&qf[ob] = *(const u32*)&qt[ib];
  *(u32*)&kf[ob] = *(const u32*)&kt[ib];
  float x0 = bf2f(qrt[ib]), x1 = bf2f(qrt[ib+1]);
  *(u32*)&qf[ob+64] = (u32)f2bf(x0*c - x1*sn) | ((u32)f2bf(x0*sn + x1*c) << 16);
  x0 = bf2f(krt[ib]); x1 = bf2f(krt[ib+1]);
  *(u32*)&kf[ob+64] = (u32)f2bf(x0*c - x1*sn) | ((u32)f2bf(x0*sn + x1*c) << 16);
}

// row softmax of scores/8, in place (bf16), row length 2048
__global__ void softmax_k(u16* __restrict__ sc)
{
  const long row = blockIdx.x;
  const int t = threadIdx.x;
  u16* p = sc + row*2048;
  const uint4 raw = ((const uint4*)p)[t];
  float v[8];
  v[0]=bf2f((u16)(raw.x&0xffffu)); v[1]=bf2f((u16)(raw.x>>16));
  v[2]=bf2f((u16)(raw.y&0xffffu)); v[3]=bf2f((u16)(raw.y>>16));
  v[4]=bf2f((u16)(raw.z&0xffffu)); v[5]=bf2f((u16)(raw.z>>16));
  v[6]=bf2f((u16)(raw.w&0xffffu)); v[7]=bf2f((u16)(raw.w>>16));
  float m = v[0];
  #pragma unroll
  for (int i=1;i<8;i++) m = fmaxf(m, v[i]);
  #pragma unroll
  for (int o=32;o>0;o>>=1) m = fmaxf(m, __shfl_down(m, o));
  __shared__ float redm[4], reds[4];
  if ((t&63)==0) redm[t>>6]=m;
  __syncthreads();
  m = fmaxf(fmaxf(redm[0],redm[1]), fmaxf(redm[2],redm[3]));
  float sum = 0.f;
  #pragma unroll
  for (int i=0;i<8;i++){ v[i] = expf((v[i]-m)*0.125f); sum += v[i]; }
  #pragma unroll
  for (int o=32;o>0;o>>=1) sum += __shfl_down(sum, o);
  if ((t&63)==0) reds[t>>6]=sum;
  __syncthreads();
  const float inv = 1.f/(reds[0]+reds[1]+reds[2]+reds[3]);
  uint4 o4;
  o4.x = (u32)f2bf(v[0]*inv) | ((u32)f2bf(v[1]*inv)<<16);
  o4.y = (u32)f2bf(v[2]*inv) | ((u32)f2bf(v[3]*inv)<<16);
  o4.z = (u32)f2bf(v[4]*inv) | ((u32)f2bf(v[5]*inv)<<16);
  o4.w = (u32)f2bf(v[6]*inv) | ((u32)f2bf(v[7]*inv)<<16);
  ((uint4*)p)[t] = o4;
}

// noisy top-2 router -> dense gate[NTOK][8] (2 nonzero)
__global__ void router_k(const float* __restrict__ h2, const float* __restrict__ wr,
                         const float* __restrict__ br, const float* __restrict__ wn,
                         const float* __restrict__ bn, const float* __restrict__ noise,
                         float* __restrict__ gate)
{
  const int tok = blockIdx.x, t = threadIdx.x;
  const float4 xv = ((const float4*)(h2 + (long)tok*D_))[t];
  const float xs[4] = {xv.x, xv.y, xv.z, xv.w};
  float ar[8], an[8];
  #pragma unroll
  for (int e=0;e<8;e++){ ar[e]=0.f; an[e]=0.f; }
  #pragma unroll
  for (int i=0;i<4;i++){
    const int d = t*4+i;
    const float* wrr = wr + d*8;
    const float* wnr = wn + d*8;
    #pragma unroll
    for (int e=0;e<8;e++){ ar[e] += xs[i]*wrr[e]; an[e] += xs[i]*wnr[e]; }
  }
  #pragma unroll
  for (int e=0;e<8;e++){
    #pragma unroll
    for (int o=32;o>0;o>>=1){ ar[e] += __shfl_down(ar[e], o); an[e] += __shfl_down(an[e], o); }
  }
  __shared__ float rr[4][8], rn[4][8];
  if ((t&63)==0){
    const int w4 = t>>6;
    #pragma unroll
    for (int e=0;e<8;e++){ rr[w4][e]=ar[e]; rn[w4][e]=an[e]; }
  }
  __syncthreads();
  if (t==0){
    float nz[8];
    #pragma unroll
    for (int e=0;e<8;e++){
      const float r  = rr[0][e]+rr[1][e]+rr[2][e]+rr[3][e] + br[e];
      const float ns = rn[0][e]+rn[1][e]+rn[2][e]+rn[3][e] + bn[e];
      const float sp = (ns > 20.f) ? ns : log1pf(expf(ns));
      nz[e] = r + noise[(long)tok*8+e]*sp;
    }
    int i0 = 0;
    #pragma unroll
    for (int e=1;e<8;e++) if (nz[e] > nz[i0]) i0 = e;
    int i1 = 0; float best = -3.0e38f;
    #pragma unroll
    for (int e=0;e<8;e++) if (e != i0 && nz[e] > best){ best = nz[e]; i1 = e; }
    const float e1  = expf(nz[i1]-nz[i0]);
    const float inv = 1.f/(1.f+e1);
    float go[8];
    #pragma unroll
    for (int e=0;e<8;e++) go[e]=0.f;
    go[i0] = inv; go[i1] = e1*inv;
    #pragma unroll
    for (int e=0;e<8;e++) gate[(long)tok*8+e] = go[e];
  }
}

__global__ void combine_k(const float* __restrict__ a, const float* __restrict__ b,
                          const float* __restrict__ c, const float* __restrict__ d,
                          float* __restrict__ o, long n4)
{
  long i = (long)blockIdx.x*blockDim.x + threadIdx.x;
  const long stride = (long)gridDim.x*blockDim.x;
  for (; i<n4; i+=stride){
    const float4 va = ((const float4*)a)[i];
    const float4 vb = ((const float4*)b)[i];
    const float4 vc = ((const float4*)c)[i];
    const float4 vd = ((const float4*)d)[i];
    ((float4*)o)[i] = make_float4(va.x+vb.x+vc.x+vd.x, va.y+vb.y+vc.y+vd.y,
                                  va.z+vb.z+vc.z+vd.z, va.w+vb.w+vc.w+vd.w);
  }
}

// ---------------------------------------------------------------------------
extern "C" void kernel_launch(void* const* d_in, const int* in_sizes, int n_in,
                              void* d_out, int out_size, void* d_ws, size_t ws_size,
                              hipStream_t stream)
{
  const float* x      = (const float*)d_in[0];
  const float* fcos   = (const float*)d_in[1];
  const float* fsin   = (const float*)d_in[2];
  const float* rnoise = (const float*)d_in[3];
  const float* rms1w  = (const float*)d_in[4];
  const float* rms2w  = (const float*)d_in[5];
  const float* w_lq   = (const float*)d_in[6];
  const float* w_lkv  = (const float*)d_in[7];
  const float* w_q    = (const float*)d_in[8];
  const float* w_k    = (const float*)d_in[9];
  const float* w_v    = (const float*)d_in[10];
  const float* w_qr   = (const float*)d_in[11];
  const float* b_qr   = (const float*)d_in[12];
  const float* w_kr   = (const float*)d_in[13];
  const float* b_kr   = (const float*)d_in[14];
  const float* w_o    = (const float*)d_in[15];
  const float* b_o    = (const float*)d_in[16];
  const float* w_route= (const float*)d_in[17];
  const float* b_route= (const float*)d_in[18];
  const float* w_noise= (const float*)d_in[19];
  const float* b_noise= (const float*)d_in[20];
  const float* rW1    = (const float*)d_in[21];
  const float* rb1    = (const float*)d_in[22];
  const float* rW2    = (const float*)d_in[23];
  const float* rb2    = (const float*)d_in[24];
  const float* sW1    = (const float*)d_in[25];
  const float* sb1    = (const float*)d_in[26];
  const float* sW2    = (const float*)d_in[27];
  const float* sb2    = (const float*)d_in[28];

  if (ws_size < 195166208ULL) return;

  char* ws = (char*)d_ws;
  u16*   h_bf    = (u16*)(ws + 0);           // 4096x1024 bf16
  u16*   cq_bf   = (u16*)(ws + 8388608);     // 4096x768
  u16*   ckv_bf  = (u16*)(ws + 14680064);    // 4096x512
  u16*   v_bf    = (u16*)(ws + 18874368);    // 4096x1024
  u16*   vt      = (u16*)(ws + 27262976);    // [32][64][2048] + 256KB pad
  u16*   qf      = (u16*)(ws + 35913728);    // 4096x2048
  u16*   kf      = (u16*)(ws + 52690944);    // 4096x2048
  u16*   attn_bf = (u16*)(ws + 69468160);    // 4096x1024
  // zone (34MB): q/qr/k/kr tmp -> scores -> x1+h2f
  u16*   q_tmp   = (u16*)(ws + 77856768);
  u16*   qr_tmp  = (u16*)(ws + 86245376);
  u16*   k_tmp   = (u16*)(ws + 94633984);
  u16*   kr_tmp  = (u16*)(ws + 103022592);
  u16*   scores  = (u16*)(ws + 77856768);    // 4 heads x 2048 x 2048 (32MB)
  float* x1      = (float*)(ws + 77856768);  // 16MB
  float* h2f     = (float*)(ws + 94633984);  // 16MB
  u16*   h2_bf   = (u16*)(ws + 111411200);   // 8MB
  float* facc    = (float*)(ws + 119799808); // 16MB
  float* gate    = (float*)(ws + 136577024); // 128KB
  u16*   wlq_t   = (u16*)(ws + 136708096);
  u16*   wlkv_t  = (u16*)(ws + 138280960);
  u16*   wq_t    = (u16*)(ws + 139329536);
  u16*   wqr_t   = (u16*)(ws + 140902400);
  u16*   wk_t    = (u16*)(ws + 142475264);
  u16*   wkr_t   = (u16*)(ws + 143523840);
  u16*   wv_t    = (u16*)(ws + 145620992);
  u16*   wo_t    = (u16*)(ws + 146669568);
  u16*   W1t     = (u16*)(ws + 148766720);   // 8MB
  u16*   W2t     = (u16*)(ws + 157155328);   // 8MB
  float* facc2   = (float*)(ws + 165543936); // 16MB  (end 182.3MB)
  u16*   inter   = (u16*)(ws + 35913728);    // 32MB, overlays qf+kf (dead by then)

  const dim3 blk(256,1,1);
  #define GEMM(FL,GRID,Aa,la,sa,Bb,lb,sb,Oo,lo,so,bi,re,ga,o2,Kk,Nn) \
    gemm_k<FL><<<GRID, blk, 0, stream>>>(Aa,la,sa, Bb,lb,sb, Oo,lo,so, bi,re,ga,o2, Kk,Nn)

  // up-front weight transposes (f32 [K][N] -> bf16 [N][K])
  tpose_k<<<dim3(24,32),blk,0,stream>>>(w_lq,  wlq_t, 1024, 768);
  tpose_k<<<dim3(16,32),blk,0,stream>>>(w_lkv, wlkv_t,1024, 512);
  tpose_k<<<dim3(32,24),blk,0,stream>>>(w_q,   wq_t,   768,1024);
  tpose_k<<<dim3(32,24),blk,0,stream>>>(w_qr,  wqr_t,  768,1024);
  tpose_k<<<dim3(32,16),blk,0,stream>>>(w_k,   wk_t,   512,1024);
  tpose_k<<<dim3(32,32),blk,0,stream>>>(w_kr,  wkr_t, 1024,1024);
  tpose_k<<<dim3(32,16),blk,0,stream>>>(w_v,   wv_t,   512,1024);
  tpose_k<<<dim3(32,32),blk,0,stream>>>(w_o,   wo_t,  1024,1024);

  // h = rmsnorm(x) -> bf16
  rmsnorm_k<false><<<NTOK, blk, 0, stream>>>(x, rms1w, h_bf, nullptr);

  // latent projections
  GEMM(F_OUTBF16, dim3(6,32,1),  h_bf,1024,0,  wlq_t,1024,0,  cq_bf,768,0,  nullptr,nullptr,nullptr,nullptr, 1024, 768);
  GEMM(F_OUTBF16, dim3(4,32,1),  h_bf,1024,0,  wlkv_t,1024,0, ckv_bf,512,0, nullptr,nullptr,nullptr,nullptr, 1024, 512);

  // q/qr/k/kr/v
  GEMM(F_OUTBF16,        dim3(8,32,1), cq_bf,768,0,  wq_t,768,0,   q_tmp,1024,0,  nullptr,nullptr,nullptr,nullptr, 768, 1024);
  GEMM(F_OUTBF16|F_BIAS, dim3(8,32,1), cq_bf,768,0,  wqr_t,768,0,  qr_tmp,1024,0, b_qr,nullptr,nullptr,nullptr,   768, 1024);
  GEMM(F_OUTBF16,        dim3(8,32,1), ckv_bf,512,0, wk_t,512,0,   k_tmp,1024,0,  nullptr,nullptr,nullptr,nullptr, 512, 1024);
  GEMM(F_OUTBF16|F_BIAS, dim3(8,32,1), h_bf,1024,0,  wkr_t,1024,0, kr_tmp,1024,0, b_kr,nullptr,nullptr,nullptr,  1024, 1024);
  GEMM(F_OUTBF16,        dim3(8,32,1), ckv_bf,512,0, wv_t,512,0,   v_bf,1024,0,   nullptr,nullptr,nullptr,nullptr, 512, 1024);

  rope_concat_k<<<8192, blk, 0, stream>>>(q_tmp, qr_tmp, k_tmp, kr_tmp, fcos, fsin, qf, kf);
  vt_k<<<dim3(64,2,32), blk, 0, stream>>>(v_bf, vt);

  // attention: 8 chunks of 4 heads (scores chunk = 32MB, L3-resident)
  for (int c=0;c<8;c++){
    const int b = c >> 2, h0 = (c & 3) * 4;
    const u16* qfs = qf + (long)b*4194304 + h0*128;
    const u16* kfs = kf + (long)b*4194304 + h0*128;
    GEMM(F_OUTBF16, dim3(16,16,4), qfs,2048,128, kfs,2048,128, scores,2048,4194304L,
         nullptr,nullptr,nullptr,nullptr, 128, 2048);
    softmax_k<<<8192, blk, 0, stream>>>(scores);
    const u16* vs = vt + (long)(b*16 + h0)*131072;
    u16* ao = attn_bf + (long)b*2097152 + h0*64;
    GEMM(F_OUTBF16, dim3(1,16,4), scores,2048,4194304L, vs,2048,131072L, ao,1024,64,
         nullptr,nullptr,nullptr,nullptr, 2048, 64);
  }

  // x1 = x + attn@w_o + b_o ; h2 = rmsnorm(x1)
  GEMM(F_BIAS|F_RESID, dim3(8,32,1), attn_bf,1024,0, wo_t,1024,0, x1,1024,0,
       b_o, x, nullptr,nullptr, 1024, 1024);
  rmsnorm_k<true><<<NTOK, blk, 0, stream>>>(x1, rms2w, h2_bf, h2f);

  // router + gates
  router_k<<<NTOK, blk, 0, stream>>>(h2f, w_route, b_route, w_noise, b_noise, rnoise, gate);
  hipMemsetAsync(facc,  0, 16777216, stream);
  hipMemsetAsync(facc2, 0, 16777216, stream);

  // routed experts (dense, gate-weighted accumulate; GEMM2 split-K x2)
  for (int e=0;e<8;e++){
    tpose_k<<<dim3(128,32),blk,0,stream>>>(rW1 + (long)e*4194304, W1t, 1024, 4096);
    tpose_k<<<dim3(32,128),blk,0,stream>>>(rW2 + (long)e*4194304, W2t, 4096, 1024);
    GEMM(F_OUTBF16|F_BIAS|F_RELU, dim3(32,32,1), h2_bf,1024,0, W1t,1024,0, inter,4096,0,
         rb1 + e*4096, nullptr,nullptr,nullptr, 1024, 4096);
    GEMM(F_BIAS|F_GATEACC|F_SPLITK, dim3(8,32,2), inter,4096,2048, W2t,4096,2048, facc,1024,0,
         rb2 + e*1024, nullptr, gate + e, facc2, 2048, 1024);
  }
  // shared experts (gate = 1)
  for (int j=0;j<2;j++){
    tpose_k<<<dim3(128,32),blk,0,stream>>>(sW1 + (long)j*4194304, W1t, 1024, 4096);
    tpose_k<<<dim3(32,128),blk,0,stream>>>(sW2 + (long)j*4194304, W2t, 4096, 1024);
    GEMM(F_OUTBF16|F_BIAS|F_RELU, dim3(32,32,1), h2_bf,1024,0, W1t,1024,0, inter,4096,0,
         sb1 + j*4096, nullptr,nullptr,nullptr, 1024, 4096);
    GEMM(F_BIAS|F_GATEACC|F_SPLITK, dim3(8,32,2), inter,4096,2048, W2t,4096,2048, facc,1024,0,
         sb2 + j*1024, nullptr, nullptr, facc2, 2048, 1024);
  }

  // out = x1 + h2 + facc + facc2
  combine_k<<<2048, blk, 0, stream>>>(x1, h2f, facc, facc2, (float*)d_out, 1048576L);
}